// Round 6
// baseline (5198.272 us; speedup 1.0000x reference)
//
#include <hip/hip_runtime.h>
#include <hip/hip_bf16.h>
#include <hip/hip_fp8.h>

// Problem constants (fixed by the bench: B=32, T0=50, F=171, H=1024, G=300)
#define Bn   32
#define Fdim 171
#define XPAD 256             // x-region padded to 16 tiles of 16 (clean wave split)
#define Hdim 1024
#define NG   4096            // 4*H gate rows
#define K1p  1280            // layer1 K = XPAD+H = 1280 (80 tiles)
#define K2c  2048            // layer2/3 K = 2H (128 tiles)
#define KDd  1024            // decoder K = H
#define WDR  176             // decoder rows padded 171 -> 176
#define NBLK 192             // persistent grid: 3 layers x 64 unit-tiles
#define S1e  (80 * 512)      // ab1 slot BYTES (fp8, tiled [80][32][16])
#define S2e  (128 * 512)     // ab2/ab3 slot BYTES (tiled [128][32][16])

// fp8 scaling: weights *64, activations *16, both exact powers of 2.
#define SW    64.0f
#define SA    16.0f
#define INVS  (1.0f / (SW * SA))

typedef __attribute__((ext_vector_type(4))) float f32x4;
typedef unsigned char fp8;

// ---------------- static workspace layout (bytes); ab buffers are tail ----
#define ALIGN256(x) ((((size_t)(x)) + 255) & ~(size_t)255)
constexpr size_t OFF_W1  = 0;
constexpr size_t OFF_W2  = ALIGN256(OFF_W1 + (size_t)NG * K1p);
constexpr size_t OFF_W3  = ALIGN256(OFF_W2 + (size_t)NG * K2c);
constexpr size_t OFF_WD  = ALIGN256(OFF_W3 + (size_t)NG * K2c);
constexpr size_t OFF_B1  = ALIGN256(OFF_WD + (size_t)WDR * KDd);
constexpr size_t OFF_B2  = ALIGN256(OFF_B1 + (size_t)NG * 4);
constexpr size_t OFF_B3  = ALIGN256(OFF_B2 + (size_t)NG * 4);
constexpr size_t OFF_BD  = ALIGN256(OFF_B3 + (size_t)NG * 4);
constexpr size_t OFF_CB  = ALIGN256(OFF_BD + (size_t)WDR * 4);
constexpr size_t OFF_BAR = ALIGN256(OFF_CB + (size_t)3 * Bn * Hdim * 4);
constexpr size_t OFF_AB1 = ALIGN256(OFF_BAR + 2048);
// ab1: D*S1e; ab2: D*S2e; ab3: D*S2e  (D chosen from ws_size; <=32)

// gate-interleaved packed row: pr = u*64 + q*16 + rr  <->  orig row = q*1024 + u*16 + rr
__device__ __forceinline__ int orig_row(int pr) {
    int u = pr >> 6, q = (pr >> 4) & 3, rr = pr & 15;
    return q * Hdim + u * 16 + rr;
}

__device__ __forceinline__ float sigm(float x) { return 1.f / (1.f + __expf(-x)); }

__device__ __forceinline__ unsigned char f2fp8(float x) {  // OCP e4m3, RNE+sat
    __hip_fp8_e4m3 q(x);
    return (unsigned char)q.__x;
}

__device__ __forceinline__ long ld8b(const fp8* p) {   // plain cached 8B load
    return *reinterpret_cast<const long*>(p);
}
// Coherent write-through stores (agent scope, relaxed): reach the coherence
// point, no cache-wide maintenance; readers use plain cached loads + rotation.
__device__ __forceinline__ void st1c(fp8* p, unsigned char v) {
    __hip_atomic_store((unsigned char*)p, v, __ATOMIC_RELAXED, __HIP_MEMORY_SCOPE_AGENT);
}
__device__ __forceinline__ void stu64(unsigned long long* p, unsigned long long v) {
    __hip_atomic_store(p, v, __ATOMIC_RELAXED, __HIP_MEMORY_SCOPE_AGENT);
}
__device__ __forceinline__ f32x4 mfma8(long a, long b, f32x4 c) {
    return __builtin_amdgcn_mfma_f32_16x16x32_fp8_fp8(a, b, c, 0, 0, 0);
}

// A-fragment loads from tiled [k/16][b][16] fp8 state
template <int NF>
__device__ __forceinline__ void aload(const fp8* __restrict__ As, int k0,
                                      int col, int kb8, long (&a0)[NF], long (&a1)[NF]) {
#pragma unroll
    for (int i = 0; i < NF; ++i) {
        int k = k0 + i * 32 + kb8;
        const fp8* ap = As + (size_t)(k >> 4) * 512 + (k & 15);
        a0[i] = ld8b(ap + col * 16);
        a1[i] = ld8b(ap + (col + 16) * 16);
    }
}
// weight stream + MFMA accumulate (weights row-linear [gate_row][K])
template <int K, int NF>
__device__ __forceinline__ void wstream(const fp8* __restrict__ Wrow, int k0,
                                        int col, int kb8,
                                        const long (&a0)[NF], const long (&a1)[NF],
                                        f32x4 (&acc)[2][4]) {
#pragma unroll
    for (int i = 0; i < NF; ++i) {
        const fp8* wp = Wrow + (size_t)col * K + k0 + i * 32 + kb8;
#pragma unroll
        for (int q = 0; q < 4; ++q) {
            long bq = ld8b(wp + (size_t)q * 16 * K);
            acc[0][q] = mfma8(a0[i], bq, acc[0][q]);
            acc[1][q] = mfma8(a1[i], bq, acc[1][q]);
        }
    }
}

// ---------------- prep kernels ----------------
__global__ void k_pack_w1(const float* Wih, const float* Whh, fp8* dst) {
    const size_t n = (size_t)NG * K1p;
    for (size_t i = (size_t)blockIdx.x * blockDim.x + threadIdx.x; i < n;
         i += (size_t)gridDim.x * blockDim.x) {
        int pr = (int)(i / K1p), k = (int)(i % K1p);
        int ro = orig_row(pr);
        float v = 0.f;
        if (k < Fdim)       v = Wih[(size_t)ro * Fdim + k];
        else if (k >= XPAD) v = Whh[(size_t)ro * Hdim + (k - XPAD)];
        dst[i] = f2fp8(v * SW);
    }
}

__global__ void k_pack_w23(const float* Wih, const float* Whh, fp8* dst) {
    const size_t n = (size_t)NG * K2c;
    for (size_t i = (size_t)blockIdx.x * blockDim.x + threadIdx.x; i < n;
         i += (size_t)gridDim.x * blockDim.x) {
        int pr = (int)(i / K2c), k = (int)(i % K2c);
        int ro = orig_row(pr);
        float v = (k < Hdim) ? Wih[(size_t)ro * Hdim + k]
                             : Whh[(size_t)ro * Hdim + (k - Hdim)];
        dst[i] = f2fp8(v * SW);
    }
}

__global__ void k_pack_wd(const float* Wd, fp8* dst) {
    const size_t n = (size_t)WDR * KDd;
    for (size_t i = (size_t)blockIdx.x * blockDim.x + threadIdx.x; i < n;
         i += (size_t)gridDim.x * blockDim.x) {
        int r = (int)(i / KDd), k = (int)(i % KDd);
        float v = (r < Fdim) ? Wd[(size_t)r * KDd + k] : 0.f;
        dst[i] = f2fp8(v * SW);
    }
}

__global__ void k_pack_bias(const float* bi1, const float* bh1,
                            const float* bi2, const float* bh2,
                            const float* bi3, const float* bh3,
                            const float* bd,
                            float* B1, float* B2, float* B3, float* BD) {
    const int n = 3 * NG + WDR;
    for (int i = blockIdx.x * blockDim.x + threadIdx.x; i < n;
         i += gridDim.x * blockDim.x) {
        if (i < NG)            { int ro = orig_row(i);        B1[i]        = bi1[ro] + bh1[ro]; }
        else if (i < 2 * NG)   { int ro = orig_row(i - NG);   B2[i - NG]   = bi2[ro] + bh2[ro]; }
        else if (i < 3 * NG)   { int ro = orig_row(i - 2*NG); B3[i - 2*NG] = bi3[ro] + bh3[ro]; }
        else { int r = i - 3 * NG; BD[r] = (r < Fdim) ? bd[r] : 0.f; }
    }
}

// zero all rotating state slots with coherent stores (no cached copies anywhere)
__global__ void k_init(fp8* ab1, fp8* ab2, fp8* ab3, float* cb, unsigned* bar, int D) {
    const size_t n1 = (size_t)D * (S1e / 8);   // u64 count
    const size_t n2 = (size_t)D * (S2e / 8);
    const size_t nc = 3 * Bn * Hdim;
    const size_t tot = n1 + 2 * n2 + nc + 512;
    for (size_t i = (size_t)blockIdx.x * blockDim.x + threadIdx.x; i < tot;
         i += (size_t)gridDim.x * blockDim.x) {
        if (i < n1)             stu64((unsigned long long*)ab1 + i, 0ull);
        else if (i < n1 + n2)   stu64((unsigned long long*)ab2 + (i - n1), 0ull);
        else if (i < n1 + 2*n2) stu64((unsigned long long*)ab3 + (i - n1 - n2), 0ull);
        else if (i < n1 + 2*n2 + nc) cb[i - n1 - 2*n2] = 0.f;
        else bar[i - n1 - 2*n2 - nc] = 0u;
    }
}

// stage x(0) into slot 0 (tiled layout), coherent, scaled by SA
__global__ void k_stage0(const float* xseq, fp8* ab1, int T0) {
    for (int idx = blockIdx.x * blockDim.x + threadIdx.x; idx < Bn * 11 * 16;
         idx += gridDim.x * blockDim.x) {
        int fu = idx >> 9, rem = idx & 511, b = rem >> 4, jj = rem & 15;
        int f = fu * 16 + jj;
        if (f < Fdim)
            st1c(&ab1[idx], f2fp8(xseq[(size_t)b * T0 * Fdim + f] * SA));
    }
}

__global__ void k_copy_orig(const float* xseq, float* out, int T, int T0) {
    const int n = Bn * T0 * Fdim;
    const size_t base = (size_t)Bn * T * Fdim;
    for (int i = blockIdx.x * blockDim.x + threadIdx.x; i < n;
         i += gridDim.x * blockDim.x) {
        out[base + i] = xseq[i];
    }
}

// ---------------- fence-free grid barrier (flag array, relaxed atomics) ----
__device__ __forceinline__ void gbar_all(unsigned* flags, unsigned target) {
    __syncthreads();   // drains vmcnt: all state stores acked before flag
    const int tid = threadIdx.x;
    if (tid == 0)
        __hip_atomic_store(&flags[blockIdx.x], target, __ATOMIC_RELAXED,
                           __HIP_MEMORY_SCOPE_AGENT);
    if (tid < 64) {
        for (;;) {
            unsigned v0 = __hip_atomic_load(&flags[tid], __ATOMIC_RELAXED,
                                            __HIP_MEMORY_SCOPE_AGENT);
            unsigned v1 = __hip_atomic_load(&flags[tid + 64], __ATOMIC_RELAXED,
                                            __HIP_MEMORY_SCOPE_AGENT);
            unsigned v2 = __hip_atomic_load(&flags[tid + 128], __ATOMIC_RELAXED,
                                            __HIP_MEMORY_SCOPE_AGENT);
            if (__all(v0 >= target && v1 >= target && v2 >= target)) break;
            __builtin_amdgcn_s_sleep(1);
        }
    }
    asm volatile("" ::: "memory");
    __syncthreads();
}

// wait for the 11 decoder feedback flags (layer-0 blocks, mid-phase)
__device__ __forceinline__ void waitfb(unsigned* fb, unsigned target, int lane) {
    for (;;) {
        unsigned v = target;
        if (lane < 11)
            v = __hip_atomic_load(&fb[lane], __ATOMIC_RELAXED,
                                  __HIP_MEMORY_SCOPE_AGENT);
        if (__all(v >= target)) break;
        __builtin_amdgcn_s_sleep(1);
    }
    asm volatile("" ::: "memory");
}

// ---------------- persistent LSTM kernel ----------------
// grid = 192 x 512 threads (8 waves). block -> (layer = bid/64, ut = bid%64).
// ONE grid barrier per step. Decoder runs on layer-1 blocks 64..74 after barA;
// layer-0 blocks overlap the decoder chain with their h-part GEMM and gate the
// small x-part on 11 fine-grained feedback flags.
__global__ __launch_bounds__(512, 1) void k_lstm(
    const float* __restrict__ xseq, float* __restrict__ out,
    const fp8* __restrict__ W1, const fp8* __restrict__ W2,
    const fp8* __restrict__ W3, const fp8* __restrict__ WD,
    const float* __restrict__ b1, const float* __restrict__ b2,
    const float* __restrict__ b3, const float* __restrict__ bdp,
    fp8* ab1, fp8* ab2, fp8* ab3, float* cb,
    unsigned* bar, int T0, int T, int dm) {
    __shared__ float red[8][32][66];

    const int tid = threadIdx.x;
    const int w = tid >> 6;
    const int lane = tid & 63;
    const int col = lane & 15;
    const int kb8 = (lane >> 4) << 3;
    const int bid = blockIdx.x;
    const int layer = bid >> 6;
    const int ut = bid & 63;
    const bool isdec = (bid >= 64 && bid < 75);  // decoder n-tile owners
    const int dnt = bid - 64;

    unsigned* flagsA = bar;        // [0..191]
    unsigned* fb = bar + 256;      // [0..10] feedback-ready flags

    const fp8* Wl = (layer == 0) ? W1 : (layer == 1) ? W2 : W3;
    const float* bl = (layer == 0) ? b1 : (layer == 1) ? b2 : b3;
    fp8* abIn = (layer == 0) ? ab1 : (layer == 1) ? ab2 : ab3;
    const size_t Sl = (layer == 0) ? (size_t)S1e : (size_t)S2e;

    const int eb = tid >> 4;      // elementwise batch row
    const int ejj = tid & 15;     // elementwise unit-within-tile

    // software-pipelined A fragments for layers 1/2 (loaded after each barA)
    long a0p[8], a1p[8];
    if (layer != 0) aload<8>(abIn, w * 256, col, kb8, a0p, a1p);  // slot 0, t=0

    for (int t = 0; t < T; ++t) {
        const int st = t & dm;
        const int ns = (t + 1) & dm;

        // ---------- phase A: gate GEMM + state update ----------
        f32x4 acc[2][4] = {};
        if (layer == 0) {
            const fp8* As = ab1 + (size_t)st * S1e;
            const fp8* Wrow = W1 + (size_t)(ut * 64) * K1p;
            long h0[4], h1[4];
            aload<4>(As, XPAD + w * 128, col, kb8, h0, h1);       // h-part first
            wstream<K1p, 4>(Wrow, XPAD + w * 128, col, kb8, h0, h1, acc);
            if (t >= T0) waitfb(fb, (unsigned)t, lane);           // x is generated
            long x0[1], x1[1];
            aload<1>(As, w * 32, col, kb8, x0, x1);               // x-part (16 tiles)
            wstream<K1p, 1>(Wrow, w * 32, col, kb8, x0, x1, acc);
        } else {
            const fp8* Wrow = Wl + (size_t)(ut * 64) * K2c;
            wstream<K2c, 8>(Wrow, w * 256, col, kb8, a0p, a1p, acc);
        }

        __syncthreads();  // protect red[] from previous phase's readers
#pragma unroll
        for (int mt = 0; mt < 2; ++mt)
#pragma unroll
            for (int q = 0; q < 4; ++q)
#pragma unroll
                for (int r = 0; r < 4; ++r)
                    red[w][mt * 16 + (lane >> 4) * 4 + r][q * 16 + col] = acc[mt][q][r];
        __syncthreads();

        {   // gates + elementwise c/h update
            float s[4];
#pragma unroll
            for (int q = 0; q < 4; ++q) {
                float a = 0.f;
#pragma unroll
                for (int ww = 0; ww < 8; ++ww) a += red[ww][eb][q * 16 + ejj];
                s[q] = a * INVS + bl[ut * 64 + q * 16 + ejj];
            }
            size_t cidx = ((size_t)layer * Bn + eb) * Hdim + ut * 16 + ejj;
            float cold = cb[cidx];
            float cn = sigm(s[1]) * cold + sigm(s[0]) * tanhf(s[2]);
            float hn = sigm(s[3]) * tanhf(cn);
            cb[cidx] = cn;
            unsigned char hq = f2fp8(hn * SA);
            const int off = eb * 16 + ejj;
            if (layer == 0) {
                st1c(ab1 + (size_t)ns * S1e + (16 + ut) * 512 + off, hq);
                st1c(ab2 + (size_t)ns * S2e + ut * 512 + off, hq);
            } else if (layer == 1) {
                st1c(ab2 + (size_t)ns * S2e + (64 + ut) * 512 + off, hq);
                st1c(ab3 + (size_t)ns * S2e + ut * 512 + off, hq);
            } else {
                st1c(ab3 + (size_t)ns * S2e + (64 + ut) * 512 + off, hq);
            }
        }

        if (bid == 11 && t + 1 < T0) {  // stage conditioned x(t+1), tiled
            fp8* dst = ab1 + (size_t)ns * S1e;
            for (int idx = tid; idx < Bn * 11 * 16; idx += 512) {
                int fu = idx >> 9, rem = idx & 511, b = rem >> 4, jj = rem & 15;
                int f = fu * 16 + jj;
                if (f < Fdim)
                    st1c(dst + idx,
                         f2fp8(xseq[((size_t)b * T0 + t + 1) * Fdim + f] * SA));
            }
        }

        gbar_all(flagsA, (unsigned)(t + 1));

        // prefetch next-step A fragments (valid: producers done at barA).
        // For decoder blocks this overlaps next-A latency with decoder work.
        if (layer != 0)
            aload<8>(abIn + (size_t)ns * Sl, w * 256, col, kb8, a0p, a1p);

        // ---------- decoder: out(t) = nh2 @ Wd^T + bd  (blocks 64..74) ----------
        if (isdec) {
            const fp8* Ad = ab3 + (size_t)ns * S2e + 64 * 512;  // h2 tiles
            const fp8* Wrowd = WD + (size_t)(dnt * 16) * KDd;
            long d0[4], d1[4];
            aload<4>(Ad, w * 128, col, kb8, d0, d1);
            f32x4 dacc[2] = {};
#pragma unroll
            for (int i = 0; i < 4; ++i) {
                long bq = ld8b(Wrowd + (size_t)col * KDd + w * 128 + i * 32 + kb8);
                dacc[0] = mfma8(d0[i], bq, dacc[0]);
                dacc[1] = mfma8(d1[i], bq, dacc[1]);
            }
            __syncthreads();
#pragma unroll
            for (int mt = 0; mt < 2; ++mt)
#pragma unroll
                for (int r = 0; r < 4; ++r)
                    red[w][mt * 16 + (lane >> 4) * 4 + r][col] = dacc[mt][r];
            __syncthreads();
            {
                int f = dnt * 16 + ejj;
                float v = 0.f;
#pragma unroll
                for (int ww = 0; ww < 8; ++ww) v += red[ww][eb][ejj];
                v = v * INVS + bdp[f];
                if (f < Fdim) {
                    out[(size_t)eb * ((size_t)T * Fdim) + (size_t)t * Fdim + f] = v;
                    if (t >= T0 - 1)  // out(t) = x(t+1) in the generative phase
                        st1c(ab1 + (size_t)ns * S1e + dnt * 512 + eb * 16 + ejj,
                             f2fp8(v * SA));
                }
            }
            __syncthreads();  // drain feedback stores before publishing
            if (tid == 0 && t >= T0 - 1)
                __hip_atomic_store(&fb[dnt], (unsigned)(t + 1), __ATOMIC_RELAXED,
                                   __HIP_MEMORY_SCOPE_AGENT);
        }
    }
}

// ---------------- host launch ----------------
extern "C" void kernel_launch(void* const* d_in, const int* in_sizes, int n_in,
                              void* d_out, int out_size, void* d_ws, size_t ws_size,
                              hipStream_t stream) {
    const float* xseq = (const float*)d_in[0];
    const float* Wih1 = (const float*)d_in[2];
    const float* Whh1 = (const float*)d_in[3];
    const float* bih1 = (const float*)d_in[4];
    const float* bhh1 = (const float*)d_in[5];
    const float* Wih2 = (const float*)d_in[6];
    const float* Whh2 = (const float*)d_in[7];
    const float* bih2 = (const float*)d_in[8];
    const float* bhh2 = (const float*)d_in[9];
    const float* Wih3 = (const float*)d_in[10];
    const float* Whh3 = (const float*)d_in[11];
    const float* bih3 = (const float*)d_in[12];
    const float* bhh3 = (const float*)d_in[13];
    const float* Wd   = (const float*)d_in[14];
    const float* bd   = (const float*)d_in[15];

    const int T0 = in_sizes[0] / (Bn * Fdim);                 // 50
    const int T  = out_size / (Bn * Fdim) - T0;               // 350

    char* ws = (char*)d_ws;
    fp8*   pW1 = (fp8*)(ws + OFF_W1);
    fp8*   pW2 = (fp8*)(ws + OFF_W2);
    fp8*   pW3 = (fp8*)(ws + OFF_W3);
    fp8*   pWD = (fp8*)(ws + OFF_WD);
    float* pB1 = (float*)(ws + OFF_B1);
    float* pB2 = (float*)(ws + OFF_B2);
    float* pB3 = (float*)(ws + OFF_B3);
    float* pBD = (float*)(ws + OFF_BD);
    float* cbp = (float*)(ws + OFF_CB);
    unsigned* bar = (unsigned*)(ws + OFF_BAR);
    float* out = (float*)d_out;

    // rotation depth: largest power-of-2 D (<=32) whose state fits in ws
    int D = 32;
    while (D > 4 &&
           OFF_AB1 + (size_t)D * ((size_t)S1e + 2 * (size_t)S2e) > ws_size)
        D >>= 1;
    fp8* ab1 = (fp8*)(ws + OFF_AB1);
    fp8* ab2 = ab1 + (size_t)D * S1e;
    fp8* ab3 = ab2 + (size_t)D * S2e;

    (void)n_in;  // total need @D=32 ~= 28 MB

    hipLaunchKernelGGL(k_pack_w1, dim3(1024), dim3(256), 0, stream, Wih1, Whh1, pW1);
    hipLaunchKernelGGL(k_pack_w23, dim3(1024), dim3(256), 0, stream, Wih2, Whh2, pW2);
    hipLaunchKernelGGL(k_pack_w23, dim3(1024), dim3(256), 0, stream, Wih3, Whh3, pW3);
    hipLaunchKernelGGL(k_pack_wd, dim3(704), dim3(256), 0, stream, Wd, pWD);
    hipLaunchKernelGGL(k_pack_bias, dim3(49), dim3(256), 0, stream,
                       bih1, bhh1, bih2, bhh2, bih3, bhh3, bd, pB1, pB2, pB3, pBD);
    hipLaunchKernelGGL(k_init, dim3(2048), dim3(256), 0, stream,
                       ab1, ab2, ab3, cbp, bar, D);
    hipLaunchKernelGGL(k_stage0, dim3(22), dim3(256), 0, stream, xseq, ab1, T0);
    hipLaunchKernelGGL(k_lstm, dim3(NBLK), dim3(512), 0, stream,
                       xseq, out, pW1, pW2, pW3, pWD, pB1, pB2, pB3, pBD,
                       ab1, ab2, ab3, cbp, bar, T0, T, D - 1);
    hipLaunchKernelGGL(k_copy_orig, dim3(1069), dim3(256), 0, stream, xseq, out, T, T0);
}

// Round 7
// 4521.498 us; speedup vs baseline: 1.1497x; 1.1497x over previous
//
#include <hip/hip_runtime.h>
#include <hip/hip_bf16.h>
#include <hip/hip_fp8.h>

// Problem constants (fixed by the bench: B=32, T0=50, F=171, H=1024, G=300)
#define Bn   32
#define Fdim 171
#define XPAD 256             // x-region padded to 16 tiles of 16 (clean wave split)
#define Hdim 1024
#define NG   4096            // 4*H gate rows
#define K1p  1280            // layer1 K = XPAD+H = 1280 (80 tiles)
#define K2c  2048            // layer2/3 K = 2H (128 tiles)
#define KDd  1024            // decoder K = H
#define WDR  176             // decoder rows padded 171 -> 176
#define NBLK 192             // persistent grid: 3 layers x 64 unit-tiles
#define S1e  (80 * 512)      // ab1 slot BYTES (fp8, tiled [80][32][16])
#define S2e  (128 * 512)     // ab2/ab3 slot BYTES (tiled [128][32][16])

// fp8 scaling: weights *64, activations *16, both exact powers of 2.
#define SW    64.0f
#define SA    16.0f
#define INVS  (1.0f / (SW * SA))

typedef __attribute__((ext_vector_type(4))) float f32x4;
typedef unsigned char fp8;

// ---------------- static workspace layout (bytes); ab buffers are tail ----
#define ALIGN256(x) ((((size_t)(x)) + 255) & ~(size_t)255)
constexpr size_t OFF_W1  = 0;
constexpr size_t OFF_W2  = ALIGN256(OFF_W1 + (size_t)NG * K1p);
constexpr size_t OFF_W3  = ALIGN256(OFF_W2 + (size_t)NG * K2c);
constexpr size_t OFF_WD  = ALIGN256(OFF_W3 + (size_t)NG * K2c);
constexpr size_t OFF_B1  = ALIGN256(OFF_WD + (size_t)WDR * KDd);
constexpr size_t OFF_B2  = ALIGN256(OFF_B1 + (size_t)NG * 4);
constexpr size_t OFF_B3  = ALIGN256(OFF_B2 + (size_t)NG * 4);
constexpr size_t OFF_BD  = ALIGN256(OFF_B3 + (size_t)NG * 4);
constexpr size_t OFF_CB  = ALIGN256(OFF_BD + (size_t)WDR * 4);
constexpr size_t OFF_BAR = ALIGN256(OFF_CB + (size_t)3 * Bn * Hdim * 4);
constexpr size_t OFF_AB1 = ALIGN256(OFF_BAR + 16384);   // bar region: 4096 u32
// ab1: D*S1e; ab2: D*S2e; ab3: D*S2e  (D chosen from ws_size; <=32)

// bar region word-offsets (all flags padded: one u32 per 64B line)
#define FLG(i)  ((i) * 16)          // arrival flags, 192 lines
#define RELW(m) (3072 + (m) * 16)   // 4 mirrored release words
#define FBW(j)  (3200 + (j) * 16)   // 11 decoder-feedback flags

// gate-interleaved packed row: pr = u*64 + q*16 + rr  <->  orig row = q*1024 + u*16 + rr
__device__ __forceinline__ int orig_row(int pr) {
    int u = pr >> 6, q = (pr >> 4) & 3, rr = pr & 15;
    return q * Hdim + u * 16 + rr;
}

__device__ __forceinline__ float sigm(float x) { return 1.f / (1.f + __expf(-x)); }

__device__ __forceinline__ unsigned char f2fp8(float x) {  // OCP e4m3, RNE+sat
    __hip_fp8_e4m3 q(x);
    return (unsigned char)q.__x;
}

__device__ __forceinline__ long ld8b(const fp8* p) {   // plain cached 8B load
    return *reinterpret_cast<const long*>(p);
}
// Coherent write-through stores (agent scope, relaxed): reach the coherence
// point, no cache-wide maintenance; readers use plain cached loads + rotation.
__device__ __forceinline__ void st1c(fp8* p, unsigned char v) {
    __hip_atomic_store((unsigned char*)p, v, __ATOMIC_RELAXED, __HIP_MEMORY_SCOPE_AGENT);
}
__device__ __forceinline__ void stu64(unsigned long long* p, unsigned long long v) {
    __hip_atomic_store(p, v, __ATOMIC_RELAXED, __HIP_MEMORY_SCOPE_AGENT);
}
__device__ __forceinline__ unsigned ldflag(const unsigned* p) {
    return __hip_atomic_load(p, __ATOMIC_RELAXED, __HIP_MEMORY_SCOPE_AGENT);
}
__device__ __forceinline__ void stflag(unsigned* p, unsigned v) {
    __hip_atomic_store(p, v, __ATOMIC_RELAXED, __HIP_MEMORY_SCOPE_AGENT);
}
__device__ __forceinline__ f32x4 mfma8(long a, long b, f32x4 c) {
    return __builtin_amdgcn_mfma_f32_16x16x32_fp8_fp8(a, b, c, 0, 0, 0);
}

// A-fragment loads from tiled [k/16][b][16] fp8 state
template <int NF>
__device__ __forceinline__ void aload(const fp8* __restrict__ As, int k0,
                                      int col, int kb8, long (&a0)[NF], long (&a1)[NF]) {
#pragma unroll
    for (int i = 0; i < NF; ++i) {
        int k = k0 + i * 32 + kb8;
        const fp8* ap = As + (size_t)(k >> 4) * 512 + (k & 15);
        a0[i] = ld8b(ap + col * 16);
        a1[i] = ld8b(ap + (col + 16) * 16);
    }
}
// weight stream + MFMA accumulate (weights row-linear [gate_row][K])
template <int K, int NF>
__device__ __forceinline__ void wstream(const fp8* __restrict__ Wrow, int k0,
                                        int col, int kb8,
                                        const long (&a0)[NF], const long (&a1)[NF],
                                        f32x4 (&acc)[2][4]) {
#pragma unroll
    for (int i = 0; i < NF; ++i) {
        const fp8* wp = Wrow + (size_t)col * K + k0 + i * 32 + kb8;
#pragma unroll
        for (int q = 0; q < 4; ++q) {
            long bq = ld8b(wp + (size_t)q * 16 * K);
            acc[0][q] = mfma8(a0[i], bq, acc[0][q]);
            acc[1][q] = mfma8(a1[i], bq, acc[1][q]);
        }
    }
}

// ---------------- prep kernels ----------------
__global__ void k_pack_w1(const float* Wih, const float* Whh, fp8* dst) {
    const size_t n = (size_t)NG * K1p;
    for (size_t i = (size_t)blockIdx.x * blockDim.x + threadIdx.x; i < n;
         i += (size_t)gridDim.x * blockDim.x) {
        int pr = (int)(i / K1p), k = (int)(i % K1p);
        int ro = orig_row(pr);
        float v = 0.f;
        if (k < Fdim)       v = Wih[(size_t)ro * Fdim + k];
        else if (k >= XPAD) v = Whh[(size_t)ro * Hdim + (k - XPAD)];
        dst[i] = f2fp8(v * SW);
    }
}

__global__ void k_pack_w23(const float* Wih, const float* Whh, fp8* dst) {
    const size_t n = (size_t)NG * K2c;
    for (size_t i = (size_t)blockIdx.x * blockDim.x + threadIdx.x; i < n;
         i += (size_t)gridDim.x * blockDim.x) {
        int pr = (int)(i / K2c), k = (int)(i % K2c);
        int ro = orig_row(pr);
        float v = (k < Hdim) ? Wih[(size_t)ro * Hdim + k]
                             : Whh[(size_t)ro * Hdim + (k - Hdim)];
        dst[i] = f2fp8(v * SW);
    }
}

__global__ void k_pack_wd(const float* Wd, fp8* dst) {
    const size_t n = (size_t)WDR * KDd;
    for (size_t i = (size_t)blockIdx.x * blockDim.x + threadIdx.x; i < n;
         i += (size_t)gridDim.x * blockDim.x) {
        int r = (int)(i / KDd), k = (int)(i % KDd);
        float v = (r < Fdim) ? Wd[(size_t)r * KDd + k] : 0.f;
        dst[i] = f2fp8(v * SW);
    }
}

__global__ void k_pack_bias(const float* bi1, const float* bh1,
                            const float* bi2, const float* bh2,
                            const float* bi3, const float* bh3,
                            const float* bd,
                            float* B1, float* B2, float* B3, float* BD) {
    const int n = 3 * NG + WDR;
    for (int i = blockIdx.x * blockDim.x + threadIdx.x; i < n;
         i += gridDim.x * blockDim.x) {
        if (i < NG)            { int ro = orig_row(i);        B1[i]        = bi1[ro] + bh1[ro]; }
        else if (i < 2 * NG)   { int ro = orig_row(i - NG);   B2[i - NG]   = bi2[ro] + bh2[ro]; }
        else if (i < 3 * NG)   { int ro = orig_row(i - 2*NG); B3[i - 2*NG] = bi3[ro] + bh3[ro]; }
        else { int r = i - 3 * NG; BD[r] = (r < Fdim) ? bd[r] : 0.f; }
    }
}

// zero all rotating state slots with coherent stores (no cached copies anywhere)
__global__ void k_init(fp8* ab1, fp8* ab2, fp8* ab3, float* cb, unsigned* bar, int D) {
    const size_t n1 = (size_t)D * (S1e / 8);   // u64 count
    const size_t n2 = (size_t)D * (S2e / 8);
    const size_t nc = 3 * Bn * Hdim;
    const size_t tot = n1 + 2 * n2 + nc + 4096;
    for (size_t i = (size_t)blockIdx.x * blockDim.x + threadIdx.x; i < tot;
         i += (size_t)gridDim.x * blockDim.x) {
        if (i < n1)             stu64((unsigned long long*)ab1 + i, 0ull);
        else if (i < n1 + n2)   stu64((unsigned long long*)ab2 + (i - n1), 0ull);
        else if (i < n1 + 2*n2) stu64((unsigned long long*)ab3 + (i - n1 - n2), 0ull);
        else if (i < n1 + 2*n2 + nc) cb[i - n1 - 2*n2] = 0.f;
        else bar[i - n1 - 2*n2 - nc] = 0u;
    }
}

// stage x(0) into slot 0 (tiled layout), coherent, scaled by SA
__global__ void k_stage0(const float* xseq, fp8* ab1, int T0) {
    for (int idx = blockIdx.x * blockDim.x + threadIdx.x; idx < Bn * 11 * 16;
         idx += gridDim.x * blockDim.x) {
        int fu = idx >> 9, rem = idx & 511, b = rem >> 4, jj = rem & 15;
        int f = fu * 16 + jj;
        if (f < Fdim)
            st1c(&ab1[idx], f2fp8(xseq[(size_t)b * T0 * Fdim + f] * SA));
    }
}

__global__ void k_copy_orig(const float* xseq, float* out, int T, int T0) {
    const int n = Bn * T0 * Fdim;
    const size_t base = (size_t)Bn * T * Fdim;
    for (int i = blockIdx.x * blockDim.x + threadIdx.x; i < n;
         i += gridDim.x * blockDim.x) {
        out[base + i] = xseq[i];
    }
}

// ---------------- fence-free central-poller barrier ----------------
// Arrival: one relaxed store per block to its OWN 64B line (parallel at CP).
// Block 0's wave-0 scans all 192 lines (64 lanes x 3 distinct lines), then
// publishes 4 mirrored release words; every other block polls ONE mirror with
// ONE lane. Keeps coherence-point same-line traffic ~2 orders below R6's
// all-to-all poll (which serialized 12288 lane-loads on 12 lines per sweep).
__device__ __forceinline__ void gbar_all(unsigned* bar, unsigned target) {
    __syncthreads();   // drains vmcnt: all state stores acked before flag
    const int tid = threadIdx.x;
    const int bid = blockIdx.x;
    if (tid == 0)
        stflag(&bar[FLG(bid)], target);
    if (bid == 0) {
        if (tid < 64) {
            for (;;) {
                unsigned v0 = ldflag(&bar[FLG(tid)]);
                unsigned v1 = ldflag(&bar[FLG(tid + 64)]);
                unsigned v2 = ldflag(&bar[FLG(tid + 128)]);
                if (__all(v0 >= target && v1 >= target && v2 >= target)) break;
                __builtin_amdgcn_s_sleep(2);
            }
            if (tid < 4)
                stflag(&bar[RELW(tid)], target);
        }
    } else if (tid == 0) {
        unsigned* rp = &bar[RELW(bid & 3)];
        unsigned v;
        do {
            __builtin_amdgcn_s_sleep(4);
            v = ldflag(rp);
        } while (v < target);
    }
    asm volatile("" ::: "memory");
    __syncthreads();
}

// wait for the 11 decoder feedback flags (layer-0 blocks, mid-phase)
__device__ __forceinline__ void waitfb(unsigned* bar, unsigned target, int lane) {
    for (;;) {
        unsigned v = target;
        if (lane < 11)
            v = ldflag(&bar[FBW(lane)]);
        if (__all(v >= target)) break;
        __builtin_amdgcn_s_sleep(2);
    }
    asm volatile("" ::: "memory");
}

// ---------------- persistent LSTM kernel ----------------
// grid = 192 x 512 threads (8 waves). block -> (layer = bid/64, ut = bid%64).
// ONE grid barrier per step. Decoder runs on layer-1 blocks 64..74 after barA;
// layer-0 blocks overlap the decoder chain with their h-part GEMM and gate the
// small x-part on 11 fine-grained feedback flags.
__global__ __launch_bounds__(512, 1) void k_lstm(
    const float* __restrict__ xseq, float* __restrict__ out,
    const fp8* __restrict__ W1, const fp8* __restrict__ W2,
    const fp8* __restrict__ W3, const fp8* __restrict__ WD,
    const float* __restrict__ b1, const float* __restrict__ b2,
    const float* __restrict__ b3, const float* __restrict__ bdp,
    fp8* ab1, fp8* ab2, fp8* ab3, float* cb,
    unsigned* bar, int T0, int T, int dm) {
    __shared__ float red[8][32][66];

    const int tid = threadIdx.x;
    const int w = tid >> 6;
    const int lane = tid & 63;
    const int col = lane & 15;
    const int kb8 = (lane >> 4) << 3;
    const int bid = blockIdx.x;
    const int layer = bid >> 6;
    const int ut = bid & 63;
    const bool isdec = (bid >= 64 && bid < 75);  // decoder n-tile owners
    const int dnt = bid - 64;

    const fp8* Wl = (layer == 0) ? W1 : (layer == 1) ? W2 : W3;
    const float* bl = (layer == 0) ? b1 : (layer == 1) ? b2 : b3;
    fp8* abIn = (layer == 0) ? ab1 : (layer == 1) ? ab2 : ab3;
    const size_t Sl = (layer == 0) ? (size_t)S1e : (size_t)S2e;

    const int eb = tid >> 4;      // elementwise batch row
    const int ejj = tid & 15;     // elementwise unit-within-tile

    // software-pipelined A fragments for layers 1/2 (loaded after each barA)
    long a0p[8], a1p[8];
    if (layer != 0) aload<8>(abIn, w * 256, col, kb8, a0p, a1p);  // slot 0, t=0

    for (int t = 0; t < T; ++t) {
        const int st = t & dm;
        const int ns = (t + 1) & dm;

        // ---------- phase A: gate GEMM + state update ----------
        f32x4 acc[2][4] = {};
        if (layer == 0) {
            const fp8* As = ab1 + (size_t)st * S1e;
            const fp8* Wrow = W1 + (size_t)(ut * 64) * K1p;
            long h0[4], h1[4];
            aload<4>(As, XPAD + w * 128, col, kb8, h0, h1);       // h-part first
            wstream<K1p, 4>(Wrow, XPAD + w * 128, col, kb8, h0, h1, acc);
            if (t >= T0) waitfb(bar, (unsigned)t, lane);          // x is generated
            long x0[1], x1[1];
            aload<1>(As, w * 32, col, kb8, x0, x1);               // x-part (16 tiles)
            wstream<K1p, 1>(Wrow, w * 32, col, kb8, x0, x1, acc);
        } else {
            const fp8* Wrow = Wl + (size_t)(ut * 64) * K2c;
            wstream<K2c, 8>(Wrow, w * 256, col, kb8, a0p, a1p, acc);
        }

        __syncthreads();  // protect red[] from previous phase's readers
#pragma unroll
        for (int mt = 0; mt < 2; ++mt)
#pragma unroll
            for (int q = 0; q < 4; ++q)
#pragma unroll
                for (int r = 0; r < 4; ++r)
                    red[w][mt * 16 + (lane >> 4) * 4 + r][q * 16 + col] = acc[mt][q][r];
        __syncthreads();

        {   // gates + elementwise c/h update
            float s[4];
#pragma unroll
            for (int q = 0; q < 4; ++q) {
                float a = 0.f;
#pragma unroll
                for (int ww = 0; ww < 8; ++ww) a += red[ww][eb][q * 16 + ejj];
                s[q] = a * INVS + bl[ut * 64 + q * 16 + ejj];
            }
            size_t cidx = ((size_t)layer * Bn + eb) * Hdim + ut * 16 + ejj;
            float cold = cb[cidx];
            float cn = sigm(s[1]) * cold + sigm(s[0]) * tanhf(s[2]);
            float hn = sigm(s[3]) * tanhf(cn);
            cb[cidx] = cn;
            unsigned char hq = f2fp8(hn * SA);
            const int off = eb * 16 + ejj;
            if (layer == 0) {
                st1c(ab1 + (size_t)ns * S1e + (16 + ut) * 512 + off, hq);
                st1c(ab2 + (size_t)ns * S2e + ut * 512 + off, hq);
            } else if (layer == 1) {
                st1c(ab2 + (size_t)ns * S2e + (64 + ut) * 512 + off, hq);
                st1c(ab3 + (size_t)ns * S2e + ut * 512 + off, hq);
            } else {
                st1c(ab3 + (size_t)ns * S2e + (64 + ut) * 512 + off, hq);
            }
        }

        if (bid == 11 && t + 1 < T0) {  // stage conditioned x(t+1), tiled
            fp8* dst = ab1 + (size_t)ns * S1e;
            for (int idx = tid; idx < Bn * 11 * 16; idx += 512) {
                int fu = idx >> 9, rem = idx & 511, b = rem >> 4, jj = rem & 15;
                int f = fu * 16 + jj;
                if (f < Fdim)
                    st1c(dst + idx,
                         f2fp8(xseq[((size_t)b * T0 + t + 1) * Fdim + f] * SA));
            }
        }

        gbar_all(bar, (unsigned)(t + 1));

        // prefetch next-step A fragments (valid: producers done at barA).
        // For decoder blocks this overlaps next-A latency with decoder work.
        if (layer != 0)
            aload<8>(abIn + (size_t)ns * Sl, w * 256, col, kb8, a0p, a1p);

        // ---------- decoder: out(t) = nh2 @ Wd^T + bd  (blocks 64..74) ----------
        if (isdec) {
            const fp8* Ad = ab3 + (size_t)ns * S2e + 64 * 512;  // h2 tiles
            const fp8* Wrowd = WD + (size_t)(dnt * 16) * KDd;
            long d0[4], d1[4];
            aload<4>(Ad, w * 128, col, kb8, d0, d1);
            f32x4 dacc[2] = {};
#pragma unroll
            for (int i = 0; i < 4; ++i) {
                long bq = ld8b(Wrowd + (size_t)col * KDd + w * 128 + i * 32 + kb8);
                dacc[0] = mfma8(d0[i], bq, dacc[0]);
                dacc[1] = mfma8(d1[i], bq, dacc[1]);
            }
            __syncthreads();
#pragma unroll
            for (int mt = 0; mt < 2; ++mt)
#pragma unroll
                for (int r = 0; r < 4; ++r)
                    red[w][mt * 16 + (lane >> 4) * 4 + r][col] = dacc[mt][r];
            __syncthreads();
            {
                int f = dnt * 16 + ejj;
                float v = 0.f;
#pragma unroll
                for (int ww = 0; ww < 8; ++ww) v += red[ww][eb][ejj];
                v = v * INVS + bdp[f];
                if (f < Fdim) {
                    out[(size_t)eb * ((size_t)T * Fdim) + (size_t)t * Fdim + f] = v;
                    if (t >= T0 - 1)  // out(t) = x(t+1) in the generative phase
                        st1c(ab1 + (size_t)ns * S1e + dnt * 512 + eb * 16 + ejj,
                             f2fp8(v * SA));
                }
            }
            __syncthreads();  // drain feedback stores before publishing
            if (tid == 0 && t >= T0 - 1)
                stflag(&bar[FBW(dnt)], (unsigned)(t + 1));
        }
    }
}

// ---------------- host launch ----------------
extern "C" void kernel_launch(void* const* d_in, const int* in_sizes, int n_in,
                              void* d_out, int out_size, void* d_ws, size_t ws_size,
                              hipStream_t stream) {
    const float* xseq = (const float*)d_in[0];
    const float* Wih1 = (const float*)d_in[2];
    const float* Whh1 = (const float*)d_in[3];
    const float* bih1 = (const float*)d_in[4];
    const float* bhh1 = (const float*)d_in[5];
    const float* Wih2 = (const float*)d_in[6];
    const float* Whh2 = (const float*)d_in[7];
    const float* bih2 = (const float*)d_in[8];
    const float* bhh2 = (const float*)d_in[9];
    const float* Wih3 = (const float*)d_in[10];
    const float* Whh3 = (const float*)d_in[11];
    const float* bih3 = (const float*)d_in[12];
    const float* bhh3 = (const float*)d_in[13];
    const float* Wd   = (const float*)d_in[14];
    const float* bd   = (const float*)d_in[15];

    const int T0 = in_sizes[0] / (Bn * Fdim);                 // 50
    const int T  = out_size / (Bn * Fdim) - T0;               // 350

    char* ws = (char*)d_ws;
    fp8*   pW1 = (fp8*)(ws + OFF_W1);
    fp8*   pW2 = (fp8*)(ws + OFF_W2);
    fp8*   pW3 = (fp8*)(ws + OFF_W3);
    fp8*   pWD = (fp8*)(ws + OFF_WD);
    float* pB1 = (float*)(ws + OFF_B1);
    float* pB2 = (float*)(ws + OFF_B2);
    float* pB3 = (float*)(ws + OFF_B3);
    float* pBD = (float*)(ws + OFF_BD);
    float* cbp = (float*)(ws + OFF_CB);
    unsigned* bar = (unsigned*)(ws + OFF_BAR);
    float* out = (float*)d_out;

    // rotation depth: largest power-of-2 D (<=32) whose state fits in ws
    int D = 32;
    while (D > 4 &&
           OFF_AB1 + (size_t)D * ((size_t)S1e + 2 * (size_t)S2e) > ws_size)
        D >>= 1;
    fp8* ab1 = (fp8*)(ws + OFF_AB1);
    fp8* ab2 = ab1 + (size_t)D * S1e;
    fp8* ab3 = ab2 + (size_t)D * S2e;

    (void)n_in;  // total need @D=32 ~= 28 MB

    hipLaunchKernelGGL(k_pack_w1, dim3(1024), dim3(256), 0, stream, Wih1, Whh1, pW1);
    hipLaunchKernelGGL(k_pack_w23, dim3(1024), dim3(256), 0, stream, Wih2, Whh2, pW2);
    hipLaunchKernelGGL(k_pack_w23, dim3(1024), dim3(256), 0, stream, Wih3, Whh3, pW3);
    hipLaunchKernelGGL(k_pack_wd, dim3(704), dim3(256), 0, stream, Wd, pWD);
    hipLaunchKernelGGL(k_pack_bias, dim3(49), dim3(256), 0, stream,
                       bih1, bhh1, bih2, bhh2, bih3, bhh3, bd, pB1, pB2, pB3, pBD);
    hipLaunchKernelGGL(k_init, dim3(2048), dim3(256), 0, stream,
                       ab1, ab2, ab3, cbp, bar, D);
    hipLaunchKernelGGL(k_stage0, dim3(22), dim3(256), 0, stream, xseq, ab1, T0);
    hipLaunchKernelGGL(k_lstm, dim3(NBLK), dim3(512), 0, stream,
                       xseq, out, pW1, pW2, pW3, pWD, pB1, pB2, pB3, pBD,
                       ab1, ab2, ab3, cbp, bar, T0, T, D - 1);
    hipLaunchKernelGGL(k_copy_orig, dim3(1069), dim3(256), 0, stream, xseq, out, T, T0);
}